// Round 13
// baseline (239.827 us; speedup 1.0000x reference)
//
#include <hip/hip_runtime.h>

#define EPSF 1e-9f

typedef __bf16 bf16x8 __attribute__((ext_vector_type(8)));
typedef float  f32x4  __attribute__((ext_vector_type(4)));
typedef unsigned short ushort_t;
typedef unsigned int uint_t;
typedef ushort_t us8 __attribute__((ext_vector_type(8)));

__device__ __forceinline__ float2 cmul(float cr, float ci, float2 v) {
    return make_float2(cr * v.x - ci * v.y, ci * v.x + cr * v.y);
}

__device__ __forceinline__ ushort_t f2bf(float f) {
    unsigned int u = __float_as_uint(f);
    u += 0x7FFFu + ((u >> 16) & 1u);   // RNE
    return (ushort_t)(u >> 16);
}

// packed pair helpers: low 16 bits = element 2l, high = 2l+1
__device__ __forceinline__ float2 bfu2(uint_t u) {
    return make_float2(__uint_as_float(u << 16), __uint_as_float(u & 0xFFFF0000u));
}
__device__ __forceinline__ uint_t packbf(float2 v) {
    return ((uint_t)f2bf(v.y) << 16) | (uint_t)f2bf(v.x);
}

// ---------------- init: zero cnt + lambda tables (block 0) ----------------
__global__ void k_init(const float* __restrict__ ldt, const float* __restrict__ llr,
                       const float* __restrict__ lim, float* __restrict__ tab,
                       int* __restrict__ cnt, int N) {
    int i = blockIdx.x * blockDim.x + threadIdx.x;
    if (i < N) cnt[i] = 0;
    if (blockIdx.x == 0 && threadIdx.x < 64) {
        int p = threadIdx.x;
        float dt  = expf(ldt[0]);
        float mag = expf(-expf(llr[p]) * dt);
        float ph  = lim[p] * dt;
        float c = cosf(ph), s = sinf(ph);
        float m2 = mag * mag, m3 = m2 * mag;
        float c2 = c * c - s * s, s2 = 2.f * c * s;
        float c3 = c2 * c - s2 * s, s3 = s2 * c + c2 * s;
        tab[p]        = c * mag;          tab[64 + p]  = s * mag;          // L1
        tab[128 + p]  = c * (1.f - mag);  tab[192 + p] = s * (1.f - mag);  // O1
        tab[256 + p]  = c2 * m2;          tab[320 + p] = s2 * m2;          // L2
        tab[384 + p]  = c3 * m3;          tab[448 + p] = s3 * m3;          // L3
    }
}

// ---------------- prep: all 3 weights -> bf16 B-fragment layout, one launch ----------------
__global__ void k_prepw3(const float* __restrict__ W1, const float* __restrict__ W2,
                         const float* __restrict__ Wp, ushort_t* __restrict__ wb1,
                         ushort_t* __restrict__ wb2, ushort_t* __restrict__ wpb) {
    int tid = blockIdx.x * blockDim.x + threadIdx.x;
    const float* w; ushort_t* wb; int ncols, nsteps;
    if (tid < 4096)       { w = W1; wb = wb1; ncols = 256; nsteps = 4; }
    else if (tid < 8192)  { tid -= 4096; w = W2; wb = wb2; ncols = 256; nsteps = 4; }
    else                  { tid -= 8192; w = Wp; wb = wpb; ncols = 128; nsteps = 8; }
    int l  = tid & 63;
    int s  = (tid >> 6) % nsteps;
    int nt = tid / (64 * nsteps);
    int col = nt * 16 + (l & 15);
    int kb  = s * 32 + (l >> 4) * 8;
    us8 d;
#pragma unroll
    for (int j = 0; j < 8; ++j) d[j] = f2bf(w[(size_t)(kb + j) * ncols + col]);
    *(us8*)(wb + (size_t)tid * 8) = d;
}

// ---------------- MFMA fused MLP -> bf16 xpb (block-cooperative) ----------------
__global__ void __launch_bounds__(256)
k_mlpf(const float* __restrict__ x, const ushort_t* __restrict__ wb1,
       const ushort_t* __restrict__ wb2, const ushort_t* __restrict__ wpb,
       const float* __restrict__ bp, ushort_t* __restrict__ xpb, int Mt) {
    __shared__ ushort_t hs[2][4096];   // 16KB: per-mtile 16x256 bf16 H (swizzled), block-shared
    const int wid = threadIdx.x >> 6, l = threadIdx.x & 63;
    const int mt0 = blockIdx.x * 2;
    const bool has1 = (mt0 + 1) < Mt;
    const int llo = l & 15, lhi = l >> 4;

    bf16x8 af[2][4];
#pragma unroll
    for (int m = 0; m < 2; ++m) {
        int mt = (m == 1 && !has1) ? mt0 : (mt0 + m);   // clamp tail
        const float* xr = x + (size_t)(mt * 16 + llo) * 128 + lhi * 8;
#pragma unroll
        for (int s = 0; s < 4; ++s) {
            float4 v0 = *(const float4*)(xr + s * 32);
            float4 v1 = *(const float4*)(xr + s * 32 + 4);
            us8 d;
            d[0] = f2bf(v0.x); d[1] = f2bf(v0.y); d[2] = f2bf(v0.z); d[3] = f2bf(v0.w);
            d[4] = f2bf(v1.x); d[5] = f2bf(v1.y); d[6] = f2bf(v1.z); d[7] = f2bf(v1.w);
            af[m][s] = *(bf16x8*)&d;
        }
    }

    const bf16x8* B1 = (const bf16x8*)wb1;
    const bf16x8* B2 = (const bf16x8*)wb2;
    const bf16x8* BP = (const bf16x8*)wpb;
    const f32x4 zero = {0.f, 0.f, 0.f, 0.f};

    // ---- Phase 1: GEMM1/2 + silu; wave w owns nt = 4w..4w+3 ----
#pragma unroll
    for (int j = 0; j < 4; ++j) {
        int nt = wid * 4 + j;
        bf16x8 b1[4], b2[4];
#pragma unroll
        for (int s = 0; s < 4; ++s) {
            b1[s] = B1[(nt * 4 + s) * 64 + l];
            b2[s] = B2[(nt * 4 + s) * 64 + l];
        }
#pragma unroll
        for (int m = 0; m < 2; ++m) {
            f32x4 a1 = zero, a2 = zero;
#pragma unroll
            for (int s = 0; s < 4; ++s) {
                a1 = __builtin_amdgcn_mfma_f32_16x16x32_bf16(af[m][s], b1[s], a1, 0, 0, 0);
                a2 = __builtin_amdgcn_mfma_f32_16x16x32_bf16(af[m][s], b2[s], a2, 0, 0, 0);
            }
#pragma unroll
            for (int i = 0; i < 4; ++i) {
                float g = a1[i];
                float hv = (g / (1.f + __expf(-g))) * a2[i];
                int r = 4 * lhi + i;
                int byte = (r << 9) + ((nt * 16 + llo) << 1);  // row stride 512B (256 bf16)
                byte ^= (r & 7) << 4;
                hs[m][byte >> 1] = f2bf(hv);
            }
        }
    }
    __syncthreads();

    // ---- Phase 2: GEMM3 over K=256; wave w owns nt3 = 2w, 2w+1 ----
#pragma unroll
    for (int j = 0; j < 2; ++j) {
        int nt3 = wid * 2 + j;
        f32x4 acc0 = zero, acc1 = zero;
#pragma unroll
        for (int sg = 0; sg < 8; ++sg) {
            bf16x8 bw = BP[(nt3 * 8 + sg) * 64 + l];
            int byte = (llo << 9) + (sg << 6) + (lhi << 4);
            byte ^= (llo & 7) << 4;
            bf16x8 h0 = *(const bf16x8*)((const char*)hs[0] + byte);
            acc0 = __builtin_amdgcn_mfma_f32_16x16x32_bf16(h0, bw, acc0, 0, 0, 0);
            bf16x8 h1 = *(const bf16x8*)((const char*)hs[1] + byte);
            acc1 = __builtin_amdgcn_mfma_f32_16x16x32_bf16(h1, bw, acc1, 0, 0, 0);
        }
        float bpv = bp[nt3 * 16 + llo];
        {
            const int row0 = mt0 * 16;
#pragma unroll
            for (int i = 0; i < 4; ++i) {
                int r = row0 + 4 * lhi + i;
                xpb[(size_t)r * 128 + nt3 * 16 + llo] = f2bf(acc0[i] + bpv);
            }
        }
        if (has1) {
            const int row0 = (mt0 + 1) * 16;
#pragma unroll
            for (int i = 0; i < 4; ++i) {
                int r = row0 + 4 * lhi + i;
                xpb[(size_t)r * 128 + nt3 * 16 + llo] = f2bf(acc1[i] + bpv);
            }
        }
    }
}

// ---------------- CSR build (by dst). in-deg == out-deg for this edge list ----------------
__global__ void k_hist(const int* __restrict__ ei, int E, int* __restrict__ cnt) {
    int e = blockIdx.x * blockDim.x + threadIdx.x;
    if (e < E) atomicAdd(&cnt[ei[E + e]], 1);      // histogram over dst
}

__global__ void __launch_bounds__(256)
k_scanA(const int* __restrict__ cnt, int N, int* __restrict__ bsum) {
    __shared__ int s[256];
    int t = threadIdx.x;
    int i = blockIdx.x * 256 + t;
    int v = (i < N) ? cnt[i] : 0;
    s[t] = v;
    __syncthreads();
#pragma unroll
    for (int d = 128; d > 0; d >>= 1) {
        if (t < d) s[t] += s[t + d];
        __syncthreads();
    }
    if (t == 0) bsum[blockIdx.x] = s[0];
}

__global__ void __launch_bounds__(1024)
k_scanB(const int* __restrict__ bsum, int NB, int* __restrict__ bpre,
        int* __restrict__ offN) {
    __shared__ int s[1024];
    int t = threadIdx.x;
    int v = (t < NB) ? bsum[t] : 0;
    s[t] = v;
    __syncthreads();
    for (int d = 1; d < 1024; d <<= 1) {
        int u = (t >= d) ? s[t - d] : 0;
        __syncthreads();
        s[t] += u;
        __syncthreads();
    }
    if (t < NB) bpre[t] = s[t] - v;          // exclusive
    if (t == NB - 1) *offN = s[t];           // total
}

__global__ void __launch_bounds__(256)
k_scanC(const int* __restrict__ cnt, int N, const int* __restrict__ bpre,
        int* __restrict__ off, int* __restrict__ cursor, float* __restrict__ bv) {
    __shared__ int s[256];
    int t = threadIdx.x;
    int i = blockIdx.x * 256 + t;
    int v = (i < N) ? cnt[i] : 0;
    s[t] = v;
    __syncthreads();
    for (int d = 1; d < 256; d <<= 1) {
        int u = (t >= d) ? s[t - d] : 0;
        __syncthreads();
        s[t] += u;
        __syncthreads();
    }
    if (i < N) {
        int excl = bpre[blockIdx.x] + s[t] - v;
        off[i] = excl;
        cursor[i] = excl;
        bv[i] = (v > 1) ? (-1.f / ((float)v - 1.f + EPSF)) : 0.f;
    }
}

// fill packed edge records: (src, bv[src]) -> one 8B load per edge in the passes
__global__ void k_fill(const int* __restrict__ ei, int E, const float* __restrict__ bv,
                       int* __restrict__ cursor, uint2* __restrict__ csrb) {
    int e = blockIdx.x * blockDim.x + threadIdx.x;
    if (e < E) {
        int s = ei[e], d = ei[E + e];
        int p = atomicAdd(&cursor[d], 1);
        csrb[p] = make_uint2((uint_t)s, __float_as_uint(bv[s]));
    }
}

// ---------------- fused gather + node passes (one wave per node, bf16 tables, x8 unroll) ----------------
__global__ void __launch_bounds__(256)
k_passA(const ushort_t* __restrict__ xpb, const uint2* __restrict__ eb,
        const int* __restrict__ off, const float* __restrict__ tab,
        ushort_t* __restrict__ Xbb, ushort_t* __restrict__ a1b, int N) {
    int tid = blockIdx.x * blockDim.x + threadIdx.x;
    int v = tid >> 6, l = tid & 63;
    if (v >= N) return;
    int beg = off[v], end = off[v + 1];
    float2 m0 = make_float2(0.f, 0.f), xb = make_float2(0.f, 0.f);
    const uint_t* tb = (const uint_t*)xpb;
    int k = beg;
    for (; k + 7 < end; k += 8) {
        uint2 e[8];
#pragma unroll
        for (int j = 0; j < 8; ++j) e[j] = eb[k + j];
        uint_t u[8];
#pragma unroll
        for (int j = 0; j < 8; ++j) u[j] = tb[(size_t)e[j].x * 64 + l];
#pragma unroll
        for (int j = 0; j < 8; ++j) {
            float b = __uint_as_float(e[j].y);
            float2 t0 = bfu2(u[j]);
            m0.x += t0.x; m0.y += t0.y;
            xb.x += b * t0.x; xb.y += b * t0.y;
        }
    }
    for (; k < end; ++k) {
        uint2 e0 = eb[k];
        float2 t0 = bfu2(tb[(size_t)e0.x * 64 + l]);
        float b0 = __uint_as_float(e0.y);
        m0.x += t0.x; m0.y += t0.y;
        xb.x += b0 * t0.x; xb.y += b0 * t0.y;
    }
    ((uint_t*)Xbb)[(size_t)v * 64 + l] = packbf(xb);
    float2 xv = bfu2(tb[(size_t)v * 64 + l]);
    int dg = end - beg;
    float L1r = tab[l], L1i = tab[64 + l], O1r = tab[128 + l], O1i = tab[192 + l];
    float Q = 1.f / ((float)dg - 1.f + EPSF);
    float2 t1 = cmul(O1r, O1i, xv);
    float2 t2 = cmul(L1r, L1i, m0);
    float2 a = make_float2(t1.x + Q * t2.x, t1.y + Q * t2.y);
    if (dg == 1) a = xv;
    ((uint_t*)a1b)[(size_t)v * 64 + l] = packbf(a);
}

__global__ void __launch_bounds__(256)
k_passB(const ushort_t* __restrict__ xpb, const ushort_t* __restrict__ a1b,
        const uint2* __restrict__ eb, const int* __restrict__ off,
        const float* __restrict__ tab, ushort_t* __restrict__ ab1b,
        float* __restrict__ Bv, float* __restrict__ B2v,
        ushort_t* __restrict__ a2b, int N) {
    int tid = blockIdx.x * blockDim.x + threadIdx.x;
    int v = tid >> 6, l = tid & 63;
    if (v >= N) return;
    int beg = off[v], end = off[v + 1];
    float2 A1 = make_float2(0.f, 0.f), ab = make_float2(0.f, 0.f);
    float Bs = 0.f, B2s = 0.f;
    const uint_t* tb = (const uint_t*)a1b;
    int k = beg;
    for (; k + 7 < end; k += 8) {
        uint2 e[8];
#pragma unroll
        for (int j = 0; j < 8; ++j) e[j] = eb[k + j];
        uint_t u[8];
#pragma unroll
        for (int j = 0; j < 8; ++j) u[j] = tb[(size_t)e[j].x * 64 + l];
#pragma unroll
        for (int j = 0; j < 8; ++j) {
            float b = __uint_as_float(e[j].y);
            float2 t0 = bfu2(u[j]);
            A1.x += t0.x; A1.y += t0.y;
            ab.x += b * t0.x; ab.y += b * t0.y;
            Bs += b; B2s += b * b;
        }
    }
    for (; k < end; ++k) {
        uint2 e0 = eb[k];
        float2 t0 = bfu2(tb[(size_t)e0.x * 64 + l]);
        float b0 = __uint_as_float(e0.y);
        A1.x += t0.x; A1.y += t0.y;
        ab.x += b0 * t0.x; ab.y += b0 * t0.y;
        Bs += b0; B2s += b0 * b0;
    }
    ((uint_t*)ab1b)[(size_t)v * 64 + l] = packbf(ab);
    if (l == 0) { Bv[v] = Bs; B2v[v] = B2s; }
    float2 xv = bfu2(((const uint_t*)xpb)[(size_t)v * 64 + l]);
    int dg = end - beg;
    float L1r = tab[l], L1i = tab[64 + l], O1r = tab[128 + l], O1i = tab[192 + l];
    float2 lx = cmul(L1r, L1i, xv);
    float2 m1 = make_float2(A1.x + Bs * lx.x, A1.y + Bs * lx.y);
    float Q = 1.f / ((float)dg - 1.f + EPSF);
    float2 t1 = cmul(O1r, O1i, xv);
    float2 lm = cmul(L1r, L1i, m1);
    float2 a = make_float2(t1.x + Q * lm.x, t1.y + Q * lm.y);
    if (dg == 1) a = xv;
    ((uint_t*)a2b)[(size_t)v * 64 + l] = packbf(a);
}

__global__ void __launch_bounds__(256)
k_passC(const ushort_t* __restrict__ xpb, const ushort_t* __restrict__ a2b,
        const ushort_t* __restrict__ a1b, const ushort_t* __restrict__ Xbb,
        const float* __restrict__ bv, const float* __restrict__ Bv,
        const uint2* __restrict__ eb, const int* __restrict__ off,
        const float* __restrict__ tab, ushort_t* __restrict__ a3b, int N) {
    int tid = blockIdx.x * blockDim.x + threadIdx.x;
    int v = tid >> 6, l = tid & 63;
    if (v >= N) return;
    int beg = off[v], end = off[v + 1];
    float2 A2 = make_float2(0.f, 0.f);
    const uint_t* tb = (const uint_t*)a2b;
    int k = beg;
    for (; k + 7 < end; k += 8) {
        uint_t u[8];
#pragma unroll
        for (int j = 0; j < 8; ++j) u[j] = tb[(size_t)eb[k + j].x * 64 + l];
#pragma unroll
        for (int j = 0; j < 8; ++j) {
            float2 t0 = bfu2(u[j]);
            A2.x += t0.x; A2.y += t0.y;
        }
    }
    for (; k < end; ++k) {
        float2 t0 = bfu2(tb[(size_t)eb[k].x * 64 + l]);
        A2.x += t0.x; A2.y += t0.y;
    }
    float2 xv  = bfu2(((const uint_t*)xpb)[(size_t)v * 64 + l]);
    float2 a1v = bfu2(((const uint_t*)a1b)[(size_t)v * 64 + l]);
    float2 Xbv = bfu2(((const uint_t*)Xbb)[(size_t)v * 64 + l]);
    int dg = end - beg;
    float Bs = Bv[v], bs = bv[v];
    float L1r = tab[l], L1i = tab[64 + l], O1r = tab[128 + l], O1i = tab[192 + l];
    float L2r = tab[256 + l], L2i = tab[320 + l];
    float2 la1 = cmul(L1r, L1i, a1v);
    float2 lxb = cmul(L2r, L2i, Xbv);
    float2 m2 = make_float2(A2.x + Bs * la1.x + bs * lxb.x,
                            A2.y + Bs * la1.y + bs * lxb.y);
    float Q = 1.f / ((float)dg - 1.f + EPSF);
    float2 t1 = cmul(O1r, O1i, xv);
    float2 lm = cmul(L1r, L1i, m2);
    float2 a = make_float2(t1.x + Q * lm.x, t1.y + Q * lm.y);
    if (dg == 1) a = xv;
    ((uint_t*)a3b)[(size_t)v * 64 + l] = packbf(a);
}

__global__ void __launch_bounds__(256)
k_passD(const float* __restrict__ xin, const ushort_t* __restrict__ xpb,
        const ushort_t* __restrict__ a3b, const ushort_t* __restrict__ a2b,
        const ushort_t* __restrict__ ab1b, const float* __restrict__ bv,
        const float* __restrict__ Bv, const float* __restrict__ B2v,
        const uint2* __restrict__ eb, const int* __restrict__ off,
        const float* __restrict__ tab, float* __restrict__ out, int N) {
    int tid = blockIdx.x * blockDim.x + threadIdx.x;
    int v = tid >> 6, l = tid & 63;
    if (v >= N) return;
    int beg = off[v], end = off[v + 1];
    float2 A3 = make_float2(0.f, 0.f);
    const uint_t* tb = (const uint_t*)a3b;
    int k = beg;
    for (; k + 7 < end; k += 8) {
        uint_t u[8];
#pragma unroll
        for (int j = 0; j < 8; ++j) u[j] = tb[(size_t)eb[k + j].x * 64 + l];
#pragma unroll
        for (int j = 0; j < 8; ++j) {
            float2 t0 = bfu2(u[j]);
            A3.x += t0.x; A3.y += t0.y;
        }
    }
    for (; k < end; ++k) {
        float2 t0 = bfu2(tb[(size_t)eb[k].x * 64 + l]);
        A3.x += t0.x; A3.y += t0.y;
    }
    size_t o = (size_t)v * 128 + 2 * l;
    float2 xv  = bfu2(((const uint_t*)xpb)[(size_t)v * 64 + l]);
    float2 a2v = bfu2(((const uint_t*)a2b)[(size_t)v * 64 + l]);
    float2 Abv = bfu2(((const uint_t*)ab1b)[(size_t)v * 64 + l]);
    int dg = end - beg;
    float Bs = Bv[v], bs = bv[v], B2s = B2v[v];
    float L1r = tab[l], L1i = tab[64 + l], O1r = tab[128 + l], O1i = tab[192 + l];
    float L2r = tab[256 + l], L2i = tab[320 + l];
    float L3r = tab[384 + l], L3i = tab[448 + l];
    float2 la2 = cmul(L1r, L1i, a2v);
    float2 lab = cmul(L2r, L2i, Abv);
    float2 lx3 = cmul(L3r, L3i, xv);
    float bB2 = bs * B2s;
    float2 m3 = make_float2(A3.x + Bs * la2.x + bs * lab.x + bB2 * lx3.x,
                            A3.y + Bs * la2.y + bs * lab.y + bB2 * lx3.y);
    float2 g;
    if (dg == 0) {
        g = xv;
    } else {
        float inv = 1.f / ((float)dg + EPSF);
        float2 t1 = cmul(O1r, O1i, xv);
        float2 lm = cmul(L1r, L1i, m3);
        g = make_float2(t1.x + lm.x * inv, t1.y + lm.y * inv);
    }
    float2 xi = *(const float2*)&xin[o];
    float2 res = make_float2(xi.x + fmaxf(g.x, 0.f), xi.y + fmaxf(g.y, 0.f));
    *(float2*)&out[o] = res;
}

extern "C" void kernel_launch(void* const* d_in, const int* in_sizes, int n_in,
                              void* d_out, int out_size, void* d_ws, size_t ws_size,
                              hipStream_t stream) {
    const float* x   = (const float*)d_in[0];
    const int*   ei  = (const int*)d_in[1];
    const float* ldt = (const float*)d_in[2];
    const float* llr = (const float*)d_in[3];
    const float* lim = (const float*)d_in[4];
    const float* W1  = (const float*)d_in[5];
    const float* W2  = (const float*)d_in[6];
    const float* Wp  = (const float*)d_in[7];
    const float* bp  = (const float*)d_in[8];
    float* out = (float*)d_out;

    const int N = in_sizes[0] / 128;
    const int E = in_sizes[1] / 2;
    const size_t nd = (size_t)N * 128;
    const int Mt = (N + 15) / 16;          // 16-row m-tiles
    const int Mt2 = (Mt + 1) / 2;          // m-tile pairs (one block each)
    const int NB = (N + 255) / 256;        // scan blocks

    ushort_t* xpb  = (ushort_t*)d_ws;      // all-bf16 node tables
    ushort_t* a1b  = xpb + nd;
    ushort_t* a2b  = a1b + nd;
    ushort_t* a3b  = a2b + nd;
    ushort_t* Xbb  = a3b + nd;
    ushort_t* ab1b = Xbb + nd;

    int*   cnt    = (int*)(ab1b + nd);     // N
    int*   off    = cnt + N;               // N+4 (padded)
    int*   cursor = off + N + 4;           // N
    float* bv     = (float*)(cursor + N);  // N
    float* Bv     = bv + N;                // N
    float* B2v    = Bv + N;                // N
    float* tab    = B2v + N;               // 512
    int*   bsum   = (int*)(tab + 512);     // NB
    int*   bpre   = bsum + NB;             // NB (NB even-padded below)
    uint2* csrb   = (uint2*)(bpre + NB + (NB & 1));  // E records, 8B-aligned
    ushort_t* wb1 = (ushort_t*)(csrb + E); // 32768
    ushort_t* wb2 = wb1 + 32768;           // 32768
    ushort_t* wpb = wb2 + 32768;           // 32768

    const int nodeBlocks = (int)(((size_t)N * 64 + 255) / 256);
    const int eBlocks    = (E + 255) / 256;

    // init (zeros cnt + lambda tables) — replaces rocclr fillBuffer
    k_init<<<NB, 256, 0, stream>>>(ldt, llr, lim, tab, cnt, N);

    // bf16 weight prep (single launch) + MFMA MLP
    k_prepw3<<<48, 256, 0, stream>>>(W1, W2, Wp, wb1, wb2, wpb);
    k_mlpf<<<Mt2, 256, 0, stream>>>(x, wb1, wb2, wpb, bp, xpb, Mt);

    // CSR build (hierarchical scan) + packed (src, bv[src]) edge records
    k_hist<<<eBlocks, 256, 0, stream>>>(ei, E, cnt);
    k_scanA<<<NB, 256, 0, stream>>>(cnt, N, bsum);
    k_scanB<<<1, 1024, 0, stream>>>(bsum, NB, bpre, &off[N]);
    k_scanC<<<NB, 256, 0, stream>>>(cnt, N, bpre, off, cursor, bv);
    k_fill<<<eBlocks, 256, 0, stream>>>(ei, E, bv, cursor, csrb);

    // fused gather + node passes (all-bf16 tables, packed edges, x8 unroll)
    k_passA<<<nodeBlocks, 256, 0, stream>>>(xpb, csrb, off, tab, Xbb, a1b, N);
    k_passB<<<nodeBlocks, 256, 0, stream>>>(xpb, a1b, csrb, off, tab, ab1b, Bv, B2v, a2b, N);
    k_passC<<<nodeBlocks, 256, 0, stream>>>(xpb, a2b, a1b, Xbb, bv, Bv, csrb, off, tab, a3b, N);
    k_passD<<<nodeBlocks, 256, 0, stream>>>(x, xpb, a3b, a2b, ab1b, bv, Bv, B2v, csrb, off, tab, out, N);
}

// Round 14
// 211.863 us; speedup vs baseline: 1.1320x; 1.1320x over previous
//
#include <hip/hip_runtime.h>

#define EPSF 1e-9f

typedef __bf16 bf16x8 __attribute__((ext_vector_type(8)));
typedef float  f32x4  __attribute__((ext_vector_type(4)));
typedef unsigned short ushort_t;
typedef unsigned int uint_t;
typedef ushort_t us8 __attribute__((ext_vector_type(8)));

__device__ __forceinline__ float2 cmul(float cr, float ci, float2 v) {
    return make_float2(cr * v.x - ci * v.y, ci * v.x + cr * v.y);
}

__device__ __forceinline__ ushort_t f2bf(float f) {
    unsigned int u = __float_as_uint(f);
    u += 0x7FFFu + ((u >> 16) & 1u);   // RNE
    return (ushort_t)(u >> 16);
}

// packed pair helpers: low 16 bits = element 2l, high = 2l+1
__device__ __forceinline__ float2 bfu2(uint_t u) {
    return make_float2(__uint_as_float(u << 16), __uint_as_float(u & 0xFFFF0000u));
}
__device__ __forceinline__ uint_t packbf(float2 v) {
    return ((uint_t)f2bf(v.y) << 16) | (uint_t)f2bf(v.x);
}

// ---------------- init: zero cnt + lambda tables (block 0) ----------------
__global__ void k_init(const float* __restrict__ ldt, const float* __restrict__ llr,
                       const float* __restrict__ lim, float* __restrict__ tab,
                       int* __restrict__ cnt, int N) {
    int i = blockIdx.x * blockDim.x + threadIdx.x;
    if (i < N) cnt[i] = 0;
    if (blockIdx.x == 0 && threadIdx.x < 64) {
        int p = threadIdx.x;
        float dt  = expf(ldt[0]);
        float mag = expf(-expf(llr[p]) * dt);
        float ph  = lim[p] * dt;
        float c = cosf(ph), s = sinf(ph);
        float m2 = mag * mag, m3 = m2 * mag;
        float c2 = c * c - s * s, s2 = 2.f * c * s;
        float c3 = c2 * c - s2 * s, s3 = s2 * c + c2 * s;
        tab[p]        = c * mag;          tab[64 + p]  = s * mag;          // L1
        tab[128 + p]  = c * (1.f - mag);  tab[192 + p] = s * (1.f - mag);  // O1
        tab[256 + p]  = c2 * m2;          tab[320 + p] = s2 * m2;          // L2
        tab[384 + p]  = c3 * m3;          tab[448 + p] = s3 * m3;          // L3
    }
}

// ---------------- prep: all 3 weights -> bf16 B-fragment layout, one launch ----------------
__global__ void k_prepw3(const float* __restrict__ W1, const float* __restrict__ W2,
                         const float* __restrict__ Wp, ushort_t* __restrict__ wb1,
                         ushort_t* __restrict__ wb2, ushort_t* __restrict__ wpb) {
    int tid = blockIdx.x * blockDim.x + threadIdx.x;
    const float* w; ushort_t* wb; int ncols, nsteps;
    if (tid < 4096)       { w = W1; wb = wb1; ncols = 256; nsteps = 4; }
    else if (tid < 8192)  { tid -= 4096; w = W2; wb = wb2; ncols = 256; nsteps = 4; }
    else                  { tid -= 8192; w = Wp; wb = wpb; ncols = 128; nsteps = 8; }
    int l  = tid & 63;
    int s  = (tid >> 6) % nsteps;
    int nt = tid / (64 * nsteps);
    int col = nt * 16 + (l & 15);
    int kb  = s * 32 + (l >> 4) * 8;
    us8 d;
#pragma unroll
    for (int j = 0; j < 8; ++j) d[j] = f2bf(w[(size_t)(kb + j) * ncols + col]);
    *(us8*)(wb + (size_t)tid * 8) = d;
}

// ---------------- MFMA fused MLP -> bf16 xpb (block-cooperative) ----------------
__global__ void __launch_bounds__(256)
k_mlpf(const float* __restrict__ x, const ushort_t* __restrict__ wb1,
       const ushort_t* __restrict__ wb2, const ushort_t* __restrict__ wpb,
       const float* __restrict__ bp, ushort_t* __restrict__ xpb, int Mt) {
    __shared__ ushort_t hs[2][4096];   // 16KB: per-mtile 16x256 bf16 H (swizzled), block-shared
    const int wid = threadIdx.x >> 6, l = threadIdx.x & 63;
    const int mt0 = blockIdx.x * 2;
    const bool has1 = (mt0 + 1) < Mt;
    const int llo = l & 15, lhi = l >> 4;

    bf16x8 af[2][4];
#pragma unroll
    for (int m = 0; m < 2; ++m) {
        int mt = (m == 1 && !has1) ? mt0 : (mt0 + m);   // clamp tail
        const float* xr = x + (size_t)(mt * 16 + llo) * 128 + lhi * 8;
#pragma unroll
        for (int s = 0; s < 4; ++s) {
            float4 v0 = *(const float4*)(xr + s * 32);
            float4 v1 = *(const float4*)(xr + s * 32 + 4);
            us8 d;
            d[0] = f2bf(v0.x); d[1] = f2bf(v0.y); d[2] = f2bf(v0.z); d[3] = f2bf(v0.w);
            d[4] = f2bf(v1.x); d[5] = f2bf(v1.y); d[6] = f2bf(v1.z); d[7] = f2bf(v1.w);
            af[m][s] = *(bf16x8*)&d;
        }
    }

    const bf16x8* B1 = (const bf16x8*)wb1;
    const bf16x8* B2 = (const bf16x8*)wb2;
    const bf16x8* BP = (const bf16x8*)wpb;
    const f32x4 zero = {0.f, 0.f, 0.f, 0.f};

    // ---- Phase 1: GEMM1/2 + silu; wave w owns nt = 4w..4w+3 ----
#pragma unroll
    for (int j = 0; j < 4; ++j) {
        int nt = wid * 4 + j;
        bf16x8 b1[4], b2[4];
#pragma unroll
        for (int s = 0; s < 4; ++s) {
            b1[s] = B1[(nt * 4 + s) * 64 + l];
            b2[s] = B2[(nt * 4 + s) * 64 + l];
        }
#pragma unroll
        for (int m = 0; m < 2; ++m) {
            f32x4 a1 = zero, a2 = zero;
#pragma unroll
            for (int s = 0; s < 4; ++s) {
                a1 = __builtin_amdgcn_mfma_f32_16x16x32_bf16(af[m][s], b1[s], a1, 0, 0, 0);
                a2 = __builtin_amdgcn_mfma_f32_16x16x32_bf16(af[m][s], b2[s], a2, 0, 0, 0);
            }
#pragma unroll
            for (int i = 0; i < 4; ++i) {
                float g = a1[i];
                float hv = (g / (1.f + __expf(-g))) * a2[i];
                int r = 4 * lhi + i;
                int byte = (r << 9) + ((nt * 16 + llo) << 1);  // row stride 512B (256 bf16)
                byte ^= (r & 7) << 4;
                hs[m][byte >> 1] = f2bf(hv);
            }
        }
    }
    __syncthreads();

    // ---- Phase 2: GEMM3 over K=256; wave w owns nt3 = 2w, 2w+1 ----
#pragma unroll
    for (int j = 0; j < 2; ++j) {
        int nt3 = wid * 2 + j;
        f32x4 acc0 = zero, acc1 = zero;
#pragma unroll
        for (int sg = 0; sg < 8; ++sg) {
            bf16x8 bw = BP[(nt3 * 8 + sg) * 64 + l];
            int byte = (llo << 9) + (sg << 6) + (lhi << 4);
            byte ^= (llo & 7) << 4;
            bf16x8 h0 = *(const bf16x8*)((const char*)hs[0] + byte);
            acc0 = __builtin_amdgcn_mfma_f32_16x16x32_bf16(h0, bw, acc0, 0, 0, 0);
            bf16x8 h1 = *(const bf16x8*)((const char*)hs[1] + byte);
            acc1 = __builtin_amdgcn_mfma_f32_16x16x32_bf16(h1, bw, acc1, 0, 0, 0);
        }
        float bpv = bp[nt3 * 16 + llo];
        {
            const int row0 = mt0 * 16;
#pragma unroll
            for (int i = 0; i < 4; ++i) {
                int r = row0 + 4 * lhi + i;
                xpb[(size_t)r * 128 + nt3 * 16 + llo] = f2bf(acc0[i] + bpv);
            }
        }
        if (has1) {
            const int row0 = (mt0 + 1) * 16;
#pragma unroll
            for (int i = 0; i < 4; ++i) {
                int r = row0 + 4 * lhi + i;
                xpb[(size_t)r * 128 + nt3 * 16 + llo] = f2bf(acc1[i] + bpv);
            }
        }
    }
}

// ---------------- CSR build (by dst). in-deg == out-deg for this edge list ----------------
__global__ void k_hist(const int* __restrict__ ei, int E, int* __restrict__ cnt) {
    int e = blockIdx.x * blockDim.x + threadIdx.x;
    if (e < E) atomicAdd(&cnt[ei[E + e]], 1);      // histogram over dst
}

__global__ void __launch_bounds__(256)
k_scanA(const int* __restrict__ cnt, int N, int* __restrict__ bsum) {
    __shared__ int s[256];
    int t = threadIdx.x;
    int i = blockIdx.x * 256 + t;
    int v = (i < N) ? cnt[i] : 0;
    s[t] = v;
    __syncthreads();
#pragma unroll
    for (int d = 128; d > 0; d >>= 1) {
        if (t < d) s[t] += s[t + d];
        __syncthreads();
    }
    if (t == 0) bsum[blockIdx.x] = s[0];
}

__global__ void __launch_bounds__(1024)
k_scanB(const int* __restrict__ bsum, int NB, int* __restrict__ bpre,
        int* __restrict__ offN) {
    __shared__ int s[1024];
    int t = threadIdx.x;
    int v = (t < NB) ? bsum[t] : 0;
    s[t] = v;
    __syncthreads();
    for (int d = 1; d < 1024; d <<= 1) {
        int u = (t >= d) ? s[t - d] : 0;
        __syncthreads();
        s[t] += u;
        __syncthreads();
    }
    if (t < NB) bpre[t] = s[t] - v;          // exclusive
    if (t == NB - 1) *offN = s[t];           // total
}

__global__ void __launch_bounds__(256)
k_scanC(const int* __restrict__ cnt, int N, const int* __restrict__ bpre,
        int* __restrict__ off, int* __restrict__ cursor, float* __restrict__ bv) {
    __shared__ int s[256];
    int t = threadIdx.x;
    int i = blockIdx.x * 256 + t;
    int v = (i < N) ? cnt[i] : 0;
    s[t] = v;
    __syncthreads();
    for (int d = 1; d < 256; d <<= 1) {
        int u = (t >= d) ? s[t - d] : 0;
        __syncthreads();
        s[t] += u;
        __syncthreads();
    }
    if (i < N) {
        int excl = bpre[blockIdx.x] + s[t] - v;
        off[i] = excl;
        cursor[i] = excl;
        bv[i] = (v > 1) ? (-1.f / ((float)v - 1.f + EPSF)) : 0.f;
    }
}

// fill packed edge records: (src, bv[src]) -> one 8B load per edge in the passes
__global__ void k_fill(const int* __restrict__ ei, int E, const float* __restrict__ bv,
                       int* __restrict__ cursor, uint2* __restrict__ csrb) {
    int e = blockIdx.x * blockDim.x + threadIdx.x;
    if (e < E) {
        int s = ei[e], d = ei[E + e];
        int p = atomicAdd(&cursor[d], 1);
        csrb[p] = make_uint2((uint_t)s, __float_as_uint(bv[s]));
    }
}

// ---------------- fused gather + node passes (one wave per node, bf16 tables, x4 unroll) ----------------
__global__ void __launch_bounds__(256)
k_passA(const ushort_t* __restrict__ xpb, const uint2* __restrict__ eb,
        const int* __restrict__ off, const float* __restrict__ tab,
        ushort_t* __restrict__ Xbb, ushort_t* __restrict__ a1b, int N) {
    int tid = blockIdx.x * blockDim.x + threadIdx.x;
    int v = tid >> 6, l = tid & 63;
    if (v >= N) return;
    int beg = off[v], end = off[v + 1];
    float2 m0 = make_float2(0.f, 0.f), xb = make_float2(0.f, 0.f);
    const uint_t* tb = (const uint_t*)xpb;
    int k = beg;
    for (; k + 3 < end; k += 4) {
        uint2 e0 = eb[k], e1 = eb[k + 1], e2 = eb[k + 2], e3 = eb[k + 3];
        uint_t u0 = tb[(size_t)e0.x * 64 + l];
        uint_t u1 = tb[(size_t)e1.x * 64 + l];
        uint_t u2 = tb[(size_t)e2.x * 64 + l];
        uint_t u3 = tb[(size_t)e3.x * 64 + l];
        float b0 = __uint_as_float(e0.y), b1 = __uint_as_float(e1.y);
        float b2 = __uint_as_float(e2.y), b3 = __uint_as_float(e3.y);
        float2 t0 = bfu2(u0), t1 = bfu2(u1), t2 = bfu2(u2), t3 = bfu2(u3);
        m0.x += (t0.x + t1.x) + (t2.x + t3.x);
        m0.y += (t0.y + t1.y) + (t2.y + t3.y);
        xb.x += b0 * t0.x + b1 * t1.x + b2 * t2.x + b3 * t3.x;
        xb.y += b0 * t0.y + b1 * t1.y + b2 * t2.y + b3 * t3.y;
    }
    for (; k < end; ++k) {
        uint2 e0 = eb[k];
        float2 t0 = bfu2(tb[(size_t)e0.x * 64 + l]);
        float b0 = __uint_as_float(e0.y);
        m0.x += t0.x; m0.y += t0.y;
        xb.x += b0 * t0.x; xb.y += b0 * t0.y;
    }
    ((uint_t*)Xbb)[(size_t)v * 64 + l] = packbf(xb);
    float2 xv = bfu2(tb[(size_t)v * 64 + l]);
    int dg = end - beg;
    float L1r = tab[l], L1i = tab[64 + l], O1r = tab[128 + l], O1i = tab[192 + l];
    float Q = 1.f / ((float)dg - 1.f + EPSF);
    float2 t1 = cmul(O1r, O1i, xv);
    float2 t2 = cmul(L1r, L1i, m0);
    float2 a = make_float2(t1.x + Q * t2.x, t1.y + Q * t2.y);
    if (dg == 1) a = xv;
    ((uint_t*)a1b)[(size_t)v * 64 + l] = packbf(a);
}

__global__ void __launch_bounds__(256)
k_passB(const ushort_t* __restrict__ xpb, const ushort_t* __restrict__ a1b,
        const uint2* __restrict__ eb, const int* __restrict__ off,
        const float* __restrict__ tab, ushort_t* __restrict__ ab1b,
        float* __restrict__ Bv, float* __restrict__ B2v,
        ushort_t* __restrict__ a2b, int N) {
    int tid = blockIdx.x * blockDim.x + threadIdx.x;
    int v = tid >> 6, l = tid & 63;
    if (v >= N) return;
    int beg = off[v], end = off[v + 1];
    float2 A1 = make_float2(0.f, 0.f), ab = make_float2(0.f, 0.f);
    float Bs = 0.f, B2s = 0.f;
    const uint_t* tb = (const uint_t*)a1b;
    int k = beg;
    for (; k + 3 < end; k += 4) {
        uint2 e0 = eb[k], e1 = eb[k + 1], e2 = eb[k + 2], e3 = eb[k + 3];
        uint_t u0 = tb[(size_t)e0.x * 64 + l];
        uint_t u1 = tb[(size_t)e1.x * 64 + l];
        uint_t u2 = tb[(size_t)e2.x * 64 + l];
        uint_t u3 = tb[(size_t)e3.x * 64 + l];
        float b0 = __uint_as_float(e0.y), b1 = __uint_as_float(e1.y);
        float b2 = __uint_as_float(e2.y), b3 = __uint_as_float(e3.y);
        float2 t0 = bfu2(u0), t1 = bfu2(u1), t2 = bfu2(u2), t3 = bfu2(u3);
        A1.x += (t0.x + t1.x) + (t2.x + t3.x);
        A1.y += (t0.y + t1.y) + (t2.y + t3.y);
        ab.x += b0 * t0.x + b1 * t1.x + b2 * t2.x + b3 * t3.x;
        ab.y += b0 * t0.y + b1 * t1.y + b2 * t2.y + b3 * t3.y;
        Bs += (b0 + b1) + (b2 + b3);
        B2s += (b0 * b0 + b1 * b1) + (b2 * b2 + b3 * b3);
    }
    for (; k < end; ++k) {
        uint2 e0 = eb[k];
        float2 t0 = bfu2(tb[(size_t)e0.x * 64 + l]);
        float b0 = __uint_as_float(e0.y);
        A1.x += t0.x; A1.y += t0.y;
        ab.x += b0 * t0.x; ab.y += b0 * t0.y;
        Bs += b0; B2s += b0 * b0;
    }
    ((uint_t*)ab1b)[(size_t)v * 64 + l] = packbf(ab);
    if (l == 0) { Bv[v] = Bs; B2v[v] = B2s; }
    float2 xv = bfu2(((const uint_t*)xpb)[(size_t)v * 64 + l]);
    int dg = end - beg;
    float L1r = tab[l], L1i = tab[64 + l], O1r = tab[128 + l], O1i = tab[192 + l];
    float2 lx = cmul(L1r, L1i, xv);
    float2 m1 = make_float2(A1.x + Bs * lx.x, A1.y + Bs * lx.y);
    float Q = 1.f / ((float)dg - 1.f + EPSF);
    float2 t1 = cmul(O1r, O1i, xv);
    float2 lm = cmul(L1r, L1i, m1);
    float2 a = make_float2(t1.x + Q * lm.x, t1.y + Q * lm.y);
    if (dg == 1) a = xv;
    ((uint_t*)a2b)[(size_t)v * 64 + l] = packbf(a);
}

__global__ void __launch_bounds__(256)
k_passC(const ushort_t* __restrict__ xpb, const ushort_t* __restrict__ a2b,
        const ushort_t* __restrict__ a1b, const ushort_t* __restrict__ Xbb,
        const float* __restrict__ bv, const float* __restrict__ Bv,
        const uint2* __restrict__ eb, const int* __restrict__ off,
        const float* __restrict__ tab, ushort_t* __restrict__ a3b, int N) {
    int tid = blockIdx.x * blockDim.x + threadIdx.x;
    int v = tid >> 6, l = tid & 63;
    if (v >= N) return;
    int beg = off[v], end = off[v + 1];
    float2 A2 = make_float2(0.f, 0.f);
    const uint_t* tb = (const uint_t*)a2b;
    int k = beg;
    for (; k + 3 < end; k += 4) {
        uint2 e0 = eb[k], e1 = eb[k + 1], e2 = eb[k + 2], e3 = eb[k + 3];
        float2 t0 = bfu2(tb[(size_t)e0.x * 64 + l]);
        float2 t1 = bfu2(tb[(size_t)e1.x * 64 + l]);
        float2 t2 = bfu2(tb[(size_t)e2.x * 64 + l]);
        float2 t3 = bfu2(tb[(size_t)e3.x * 64 + l]);
        A2.x += (t0.x + t1.x) + (t2.x + t3.x);
        A2.y += (t0.y + t1.y) + (t2.y + t3.y);
    }
    for (; k < end; ++k) {
        float2 t0 = bfu2(tb[(size_t)eb[k].x * 64 + l]);
        A2.x += t0.x; A2.y += t0.y;
    }
    float2 xv  = bfu2(((const uint_t*)xpb)[(size_t)v * 64 + l]);
    float2 a1v = bfu2(((const uint_t*)a1b)[(size_t)v * 64 + l]);
    float2 Xbv = bfu2(((const uint_t*)Xbb)[(size_t)v * 64 + l]);
    int dg = end - beg;
    float Bs = Bv[v], bs = bv[v];
    float L1r = tab[l], L1i = tab[64 + l], O1r = tab[128 + l], O1i = tab[192 + l];
    float L2r = tab[256 + l], L2i = tab[320 + l];
    float2 la1 = cmul(L1r, L1i, a1v);
    float2 lxb = cmul(L2r, L2i, Xbv);
    float2 m2 = make_float2(A2.x + Bs * la1.x + bs * lxb.x,
                            A2.y + Bs * la1.y + bs * lxb.y);
    float Q = 1.f / ((float)dg - 1.f + EPSF);
    float2 t1 = cmul(O1r, O1i, xv);
    float2 lm = cmul(L1r, L1i, m2);
    float2 a = make_float2(t1.x + Q * lm.x, t1.y + Q * lm.y);
    if (dg == 1) a = xv;
    ((uint_t*)a3b)[(size_t)v * 64 + l] = packbf(a);
}

__global__ void __launch_bounds__(256)
k_passD(const float* __restrict__ xin, const ushort_t* __restrict__ xpb,
        const ushort_t* __restrict__ a3b, const ushort_t* __restrict__ a2b,
        const ushort_t* __restrict__ ab1b, const float* __restrict__ bv,
        const float* __restrict__ Bv, const float* __restrict__ B2v,
        const uint2* __restrict__ eb, const int* __restrict__ off,
        const float* __restrict__ tab, float* __restrict__ out, int N) {
    int tid = blockIdx.x * blockDim.x + threadIdx.x;
    int v = tid >> 6, l = tid & 63;
    if (v >= N) return;
    int beg = off[v], end = off[v + 1];
    float2 A3 = make_float2(0.f, 0.f);
    const uint_t* tb = (const uint_t*)a3b;
    int k = beg;
    for (; k + 3 < end; k += 4) {
        uint2 e0 = eb[k], e1 = eb[k + 1], e2 = eb[k + 2], e3 = eb[k + 3];
        float2 t0 = bfu2(tb[(size_t)e0.x * 64 + l]);
        float2 t1 = bfu2(tb[(size_t)e1.x * 64 + l]);
        float2 t2 = bfu2(tb[(size_t)e2.x * 64 + l]);
        float2 t3 = bfu2(tb[(size_t)e3.x * 64 + l]);
        A3.x += (t0.x + t1.x) + (t2.x + t3.x);
        A3.y += (t0.y + t1.y) + (t2.y + t3.y);
    }
    for (; k < end; ++k) {
        float2 t0 = bfu2(tb[(size_t)eb[k].x * 64 + l]);
        A3.x += t0.x; A3.y += t0.y;
    }
    size_t o = (size_t)v * 128 + 2 * l;
    float2 xv  = bfu2(((const uint_t*)xpb)[(size_t)v * 64 + l]);
    float2 a2v = bfu2(((const uint_t*)a2b)[(size_t)v * 64 + l]);
    float2 Abv = bfu2(((const uint_t*)ab1b)[(size_t)v * 64 + l]);
    int dg = end - beg;
    float Bs = Bv[v], bs = bv[v], B2s = B2v[v];
    float L1r = tab[l], L1i = tab[64 + l], O1r = tab[128 + l], O1i = tab[192 + l];
    float L2r = tab[256 + l], L2i = tab[320 + l];
    float L3r = tab[384 + l], L3i = tab[448 + l];
    float2 la2 = cmul(L1r, L1i, a2v);
    float2 lab = cmul(L2r, L2i, Abv);
    float2 lx3 = cmul(L3r, L3i, xv);
    float bB2 = bs * B2s;
    float2 m3 = make_float2(A3.x + Bs * la2.x + bs * lab.x + bB2 * lx3.x,
                            A3.y + Bs * la2.y + bs * lab.y + bB2 * lx3.y);
    float2 g;
    if (dg == 0) {
        g = xv;
    } else {
        float inv = 1.f / ((float)dg + EPSF);
        float2 t1 = cmul(O1r, O1i, xv);
        float2 lm = cmul(L1r, L1i, m3);
        g = make_float2(t1.x + lm.x * inv, t1.y + lm.y * inv);
    }
    float2 xi = *(const float2*)&xin[o];
    float2 res = make_float2(xi.x + fmaxf(g.x, 0.f), xi.y + fmaxf(g.y, 0.f));
    *(float2*)&out[o] = res;
}

extern "C" void kernel_launch(void* const* d_in, const int* in_sizes, int n_in,
                              void* d_out, int out_size, void* d_ws, size_t ws_size,
                              hipStream_t stream) {
    const float* x   = (const float*)d_in[0];
    const int*   ei  = (const int*)d_in[1];
    const float* ldt = (const float*)d_in[2];
    const float* llr = (const float*)d_in[3];
    const float* lim = (const float*)d_in[4];
    const float* W1  = (const float*)d_in[5];
    const float* W2  = (const float*)d_in[6];
    const float* Wp  = (const float*)d_in[7];
    const float* bp  = (const float*)d_in[8];
    float* out = (float*)d_out;

    const int N = in_sizes[0] / 128;
    const int E = in_sizes[1] / 2;
    const size_t nd = (size_t)N * 128;
    const int Mt = (N + 15) / 16;          // 16-row m-tiles
    const int Mt2 = (Mt + 1) / 2;          // m-tile pairs (one block each)
    const int NB = (N + 255) / 256;        // scan blocks

    ushort_t* xpb  = (ushort_t*)d_ws;      // all-bf16 node tables
    ushort_t* a1b  = xpb + nd;
    ushort_t* a2b  = a1b + nd;
    ushort_t* a3b  = a2b + nd;
    ushort_t* Xbb  = a3b + nd;
    ushort_t* ab1b = Xbb + nd;

    int*   cnt    = (int*)(ab1b + nd);     // N
    int*   off    = cnt + N;               // N+4 (padded)
    int*   cursor = off + N + 4;           // N
    float* bv     = (float*)(cursor + N);  // N
    float* Bv     = bv + N;                // N
    float* B2v    = Bv + N;                // N
    float* tab    = B2v + N;               // 512
    int*   bsum   = (int*)(tab + 512);     // NB
    int*   bpre   = bsum + NB;             // NB (NB even-padded below)
    uint2* csrb   = (uint2*)(bpre + NB + (NB & 1));  // E records, 8B-aligned
    ushort_t* wb1 = (ushort_t*)(csrb + E); // 32768
    ushort_t* wb2 = wb1 + 32768;           // 32768
    ushort_t* wpb = wb2 + 32768;           // 32768

    const int nodeBlocks = (int)(((size_t)N * 64 + 255) / 256);
    const int eBlocks    = (E + 255) / 256;

    // init (zeros cnt + lambda tables) — replaces rocclr fillBuffer
    k_init<<<NB, 256, 0, stream>>>(ldt, llr, lim, tab, cnt, N);

    // bf16 weight prep (single launch) + MFMA MLP
    k_prepw3<<<48, 256, 0, stream>>>(W1, W2, Wp, wb1, wb2, wpb);
    k_mlpf<<<Mt2, 256, 0, stream>>>(x, wb1, wb2, wpb, bp, xpb, Mt);

    // CSR build (hierarchical scan) + packed (src, bv[src]) edge records
    k_hist<<<eBlocks, 256, 0, stream>>>(ei, E, cnt);
    k_scanA<<<NB, 256, 0, stream>>>(cnt, N, bsum);
    k_scanB<<<1, 1024, 0, stream>>>(bsum, NB, bpre, &off[N]);
    k_scanC<<<NB, 256, 0, stream>>>(cnt, N, bpre, off, cursor, bv);
    k_fill<<<eBlocks, 256, 0, stream>>>(ei, E, bv, cursor, csrb);

    // fused gather + node passes (all-bf16 tables, packed edges, x4 unroll)
    k_passA<<<nodeBlocks, 256, 0, stream>>>(xpb, csrb, off, tab, Xbb, a1b, N);
    k_passB<<<nodeBlocks, 256, 0, stream>>>(xpb, a1b, csrb, off, tab, ab1b, Bv, B2v, a2b, N);
    k_passC<<<nodeBlocks, 256, 0, stream>>>(xpb, a2b, a1b, Xbb, bv, Bv, csrb, off, tab, a3b, N);
    k_passD<<<nodeBlocks, 256, 0, stream>>>(x, xpb, a3b, a2b, ab1b, bv, Bv, B2v, csrb, off, tab, out, N);
}